// Round 3
// baseline (152.459 us; speedup 1.0000x reference)
//
#include <hip/hip_runtime.h>

// 8-connected CCL on a 2048x2048 mask (prob > 0.5).
// Output int32: (component min flat index)+1 for fg, 0 for bg.
//
//   1. k_local   : per 64x64 tile, full union-find in LDS; parent := global
//                  index of tile root (1-based; 0 = background).
//   2. k_border  : cross-tile unions, ONE union per thread, with implied-link
//                  dedup and path-halving finds (atomicMin-safe).
//   3. k_compress: chase to true root; 1-based encoding makes the compressed
//                  value the final output directly.

#define H 2048
#define W 2048
#define NPIX (H * W)
#define TS 64

// ---------- global union-find, 1-based parents, with path halving ----------
__device__ __forceinline__ int gfind(int* __restrict__ L, int a) {
    int n = L[a];
    while (n != a + 1) {
        int p = n - 1;
        int g = L[p];                     // grandparent+1
        // Path halving. MUST be atomicMin: a plain store could overwrite a
        // concurrent union's smaller parent and disconnect components.
        // g points into the same component and only decreases -> safe.
        if (g != n) atomicMin(&L[a], g);
        a = p; n = g;
    }
    return a;
}

__device__ __forceinline__ void gunite(int* __restrict__ L, int a, int b) {
    while (true) {
        a = gfind(L, a);
        b = gfind(L, b);
        if (a == b) return;
        if (a > b) { int t = a; a = b; b = t; }
        int old = atomicMin(&L[b], a + 1);
        if (old == b + 1) return;   // attached larger root under smaller
        b = old - 1;                // raced; retry from observed parent
    }
}

// ---------- local (LDS) union-find, 0-based, -1 = background ----------
__device__ __forceinline__ int lfind(volatile int* L, int a) {
    int n = L[a];
    while (n != a) { a = n; n = L[a]; }
    return a;
}

__device__ __forceinline__ void lunite(int* L, int a, int b) {
    volatile int* Lv = L;
    while (true) {
        a = lfind(Lv, a);
        b = lfind(Lv, b);
        if (a == b) return;
        if (a > b) { int t = a; a = b; b = t; }
        int old = atomicMin(&L[b], a);
        if (old == b) return;
        b = old;
    }
}

__global__ __launch_bounds__(256)
void k_local(const float* __restrict__ prob, int* __restrict__ lab) {
    __shared__ int slab[TS * TS];
    const int x0 = blockIdx.x * TS, y0 = blockIdx.y * TS;
    const int lx = threadIdx.x;   // 0..63
    const int ty = threadIdx.y;   // 0..3

    #pragma unroll
    for (int k = 0; k < 16; ++k) {
        int ly = ty + (k << 2);
        int li = ly * TS + lx;
        bool fg = prob[(y0 + ly) * W + x0 + lx] > 0.5f;
        slab[li] = fg ? li : -1;
    }
    __syncthreads();

    // causal unions; if west fg, NW/N implied (NE never skipped)
    #pragma unroll 1
    for (int k = 0; k < 16; ++k) {
        int ly = ty + (k << 2);
        int li = ly * TS + lx;
        if (slab[li] < 0) continue;
        bool wfg = (lx > 0) && (slab[li - 1] >= 0);
        if (wfg) lunite(slab, li, li - 1);
        if (ly > 0) {
            if (!wfg) {
                if (lx > 0 && slab[li - TS - 1] >= 0) lunite(slab, li, li - TS - 1);
                if (slab[li - TS] >= 0) lunite(slab, li, li - TS);
            }
            if (lx < TS - 1 && slab[li - TS + 1] >= 0) lunite(slab, li, li - TS + 1);
        }
    }
    __syncthreads();

    #pragma unroll 1
    for (int k = 0; k < 16; ++k) {
        int ly = ty + (k << 2);
        int li = ly * TS + lx;
        int out = 0;
        if (slab[li] >= 0) {
            int r = lfind(slab, li);
            out = (y0 + (r >> 6)) * W + (x0 + (r & 63)) + 1;
        }
        lab[(y0 + ly) * W + x0 + lx] = out;
    }
}

// Cross-tile unions: 6 segments x 65536 threads, ONE union max per thread.
//   seg 0: lx==0  W   (skip if ly>0 && N fg && NW fg  -- vertical run dedup,
//                      grounds at ly==0 where W is always issued)
//   seg 1: lx==0  NW  (ly>0 only; skip if N fg: me~N intra + N~NW via seg0)
//   seg 2: lx==63 NE  (ly>0 only; skip if N fg: me~N intra + N~NE via seg0)
//   seg 3: ly==0  NW  (skip if west fg -- run-start dedup)
//   seg 4: ly==0  N   (skip if west fg)
//   seg 5: ly==0  NE  (never skipped -- anchors the horizontal dedup proof)
__global__ __launch_bounds__(256)
void k_border(int* __restrict__ lab) {
    int tid = blockIdx.x * blockDim.x + threadIdx.x;
    int seg = tid >> 16;
    int r = tid & 65535;

    if (seg < 3) {                       // vertical seams
        int y = r >> 5;
        int ly = y & (TS - 1);
        if (seg == 0) {
            int x = (r & 31) << 6;       // lx == 0
            if (x == 0) return;
            int i = y * W + x;
            int vi = lab[i];           if (!vi) return;
            int vw = lab[i - 1];       if (!vw) return;
            if (ly > 0 && lab[i - W] && lab[i - W - 1]) return;
            gunite(lab, vi - 1, vw - 1);
        } else if (seg == 1) {
            int x = (r & 31) << 6;
            if (x == 0 || ly == 0 || y == 0) return;
            int i = y * W + x;
            int vi = lab[i];           if (!vi) return;
            int vn = lab[i - W - 1];   if (!vn) return;
            if (lab[i - W]) return;      // implied
            gunite(lab, vi - 1, vn - 1);
        } else {
            int x = ((r & 31) << 6) + 63;  // lx == 63
            if (x >= W - 1 || ly == 0 || y == 0) return;
            int i = y * W + x;
            int vi = lab[i];           if (!vi) return;
            int vn = lab[i - W + 1];   if (!vn) return;
            if (lab[i - W]) return;      // implied
            gunite(lab, vi - 1, vn - 1);
        }
    } else {                             // horizontal seam rows (ly == 0)
        int x = r & (W - 1);
        int y = (r >> 11) << 6;
        if (y == 0) return;
        int i = y * W + x;
        int vi = lab[i];               if (!vi) return;
        if (seg == 3) {
            if (x == 0) return;
            int vn = lab[i - W - 1];   if (!vn) return;
            if (lab[i - 1]) return;      // run-start dedup
            gunite(lab, vi - 1, vn - 1);
        } else if (seg == 4) {
            int vn = lab[i - W];       if (!vn) return;
            if (x > 0 && lab[i - 1]) return;
            gunite(lab, vi - 1, vn - 1);
        } else {
            if (x == W - 1) return;
            int vn = lab[i - W + 1];   if (!vn) return;
            gunite(lab, vi - 1, vn - 1);
        }
    }
}

__global__ __launch_bounds__(256)
void k_compress(int* __restrict__ lab) {
    int i = blockIdx.x * blockDim.x + threadIdx.x;
    if (i >= NPIX) return;
    int v = lab[i];
    if (v == 0 || v == i + 1) return;    // bg or already root
    int r = gfind(lab, v - 1);
    lab[i] = r + 1;                      // r+1 is the global minimum -> safe plain store
}

extern "C" void kernel_launch(void* const* d_in, const int* in_sizes, int n_in,
                              void* d_out, int out_size, void* d_ws, size_t ws_size,
                              hipStream_t stream) {
    const float* prob = (const float*)d_in[0];
    int* lab = (int*)d_out;

    dim3 lgrid(W / TS, H / TS);
    dim3 lblock(TS, 4);
    k_local<<<lgrid, lblock, 0, stream>>>(prob, lab);

    const int nborder = 6 * 65536;
    k_border<<<nborder / 256, 256, 0, stream>>>(lab);

    k_compress<<<NPIX / 256, 256, 0, stream>>>(lab);
}

// Round 4
// 108.952 us; speedup vs baseline: 1.3993x; 1.3993x over previous
//
#include <hip/hip_runtime.h>

// 8-connected CCL on a 2048x2048 mask (prob > 0.5).
// Output int32: (component min flat index)+1 for fg, 0 for bg.
//
//   1. k_local   : per 64x64 tile, ballot/run-based union-find in LDS.
//                  A tile row == one wave64 ballot; labels init to run-start
//                  index (no horizontal unions at all); vertical unions fire
//                  once per run-overlap segment, conditions from row masks.
//   2. k_border  : cross-tile unions, ONE union per thread, implied-link
//                  dedup, path-halving finds (atomicMin-safe).
//   3. k_compress: chase to true root; 1-based encoding (0=bg) makes the
//                  compressed value the final output directly.

#define H 2048
#define W 2048
#define NPIX (H * W)
#define TS 64

// ---------- global union-find, 1-based parents, with path halving ----------
__device__ __forceinline__ int gfind(int* __restrict__ L, int a) {
    int n = L[a];
    while (n != a + 1) {
        int p = n - 1;
        int g = L[p];                     // grandparent+1
        // Path halving MUST be atomicMin: plain store could overwrite a
        // concurrent union's smaller parent. g is same-component & smaller.
        if (g != n) atomicMin(&L[a], g);
        a = p; n = g;
    }
    return a;
}

__device__ __forceinline__ void gunite(int* __restrict__ L, int a, int b) {
    while (true) {
        a = gfind(L, a);
        b = gfind(L, b);
        if (a == b) return;
        if (a > b) { int t = a; a = b; b = t; }
        int old = atomicMin(&L[b], a + 1);
        if (old == b + 1) return;
        b = old - 1;
    }
}

// ---------- local (LDS) union-find, 0-based, -1 = background ----------
__device__ __forceinline__ int lfind(volatile int* L, int a) {
    int n = L[a];
    while (n != a) { a = n; n = L[a]; }
    return a;
}

__device__ __forceinline__ void lunite(int* L, int a, int b) {
    volatile int* Lv = L;
    while (true) {
        a = lfind(Lv, a);
        b = lfind(Lv, b);
        if (a == b) return;
        if (a > b) { int t = a; a = b; b = t; }
        int old = atomicMin(&L[b], a);
        if (old == b) return;
        b = old;
    }
}

// run start of the run containing set-bit position p of mask m
__device__ __forceinline__ int run_start(unsigned long long m, int p) {
    if (p == 0) return 0;
    unsigned long long below = m << (64 - p);   // bit p-1 -> bit 63
    return p - __builtin_clzll(~below);         // subtract leading-ones count
}

__global__ __launch_bounds__(1024)
void k_local(const float* __restrict__ prob, int* __restrict__ lab) {
    __shared__ int slab[TS * TS];
    __shared__ unsigned long long rowmask[TS];
    const int x0 = blockIdx.x * TS, y0 = blockIdx.y * TS;
    const int lx = threadIdx.x;        // 0..63 == lane (row fits one wave)
    const int ty = threadIdx.y;        // 0..15

    unsigned long long myMask[4];
    int myS[4];

    // init: ballot row mask; label := run-start local index (kills all
    // horizontal unions and shortens trees)
    #pragma unroll
    for (int k = 0; k < 4; ++k) {
        int ly = (ty << 2) | k;
        bool fg = prob[(y0 + ly) * W + x0 + lx] > 0.5f;
        unsigned long long m = __ballot(fg);
        myMask[k] = m;
        int s = fg ? run_start(m, lx) : lx;
        myS[k] = s;
        slab[ly * TS + lx] = fg ? ly * TS + s : -1;
        if (lx == 0) rowmask[ly] = m;
    }
    __syncthreads();

    // vertical unions, once per (my-run, upper-segment) overlap:
    //   N  at leftmost covered lane of each contiguous upper segment
    //   NW only at run start, upper-left set & upper clear
    //   NE only at run end,   upper-right set & upper clear
    #pragma unroll 1
    for (int k = 0; k < 4; ++k) {
        int ly = (ty << 2) | k;
        if (ly == 0) continue;
        unsigned long long m = myMask[k];
        if (!((m >> lx) & 1)) continue;
        unsigned long long u = rowmask[ly - 1];
        int s = myS[k];
        int mylab = ly * TS + s;
        bool uc = (u >> lx) & 1;
        if (uc) {
            if (lx == s || !((u >> (lx - 1)) & 1))
                lunite(slab, mylab, (ly - 1) * TS + run_start(u, lx));
        } else {
            if (lx == s && lx > 0 && ((u >> (lx - 1)) & 1))
                lunite(slab, mylab, (ly - 1) * TS + run_start(u, lx - 1));
            bool isEnd = (lx == 63) || !((m >> (lx + 1)) & 1);
            if (isEnd && lx < 63 && ((u >> (lx + 1)) & 1))
                lunite(slab, mylab, (ly - 1) * TS + (lx + 1)); // u[lx]=0 -> run starts there
        }
    }
    __syncthreads();

    // flatten: parent := global index of tile root (= min local index)
    #pragma unroll 1
    for (int k = 0; k < 4; ++k) {
        int ly = (ty << 2) | k;
        int li = ly * TS + lx;
        int out = 0;
        if (slab[li] >= 0) {
            int r = lfind(slab, li);
            out = (y0 + (r >> 6)) * W + (x0 + (r & 63)) + 1;
        }
        lab[(y0 + ly) * W + x0 + lx] = out;
    }
}

// Cross-tile unions: 6 segments x 65536 threads, ONE union max per thread.
//   seg 0: lx==0  W   (skip if ly>0 && N fg && NW fg)
//   seg 1: lx==0  NW  (ly>0; skip if N fg)
//   seg 2: lx==63 NE  (ly>0; skip if N fg)
//   seg 3: ly==0  NW  (skip if west fg)
//   seg 4: ly==0  N   (skip if west fg)
//   seg 5: ly==0  NE  (never skipped)
__global__ __launch_bounds__(256)
void k_border(int* __restrict__ lab) {
    int tid = blockIdx.x * blockDim.x + threadIdx.x;
    int seg = tid >> 16;
    int r = tid & 65535;

    if (seg < 3) {                       // vertical seams
        int y = r >> 5;
        int ly = y & (TS - 1);
        if (seg == 0) {
            int x = (r & 31) << 6;
            if (x == 0) return;
            int i = y * W + x;
            int vi = lab[i];           if (!vi) return;
            int vw = lab[i - 1];       if (!vw) return;
            if (ly > 0 && lab[i - W] && lab[i - W - 1]) return;
            gunite(lab, vi - 1, vw - 1);
        } else if (seg == 1) {
            int x = (r & 31) << 6;
            if (x == 0 || ly == 0 || y == 0) return;
            int i = y * W + x;
            int vi = lab[i];           if (!vi) return;
            int vn = lab[i - W - 1];   if (!vn) return;
            if (lab[i - W]) return;
            gunite(lab, vi - 1, vn - 1);
        } else {
            int x = ((r & 31) << 6) + 63;
            if (x >= W - 1 || ly == 0 || y == 0) return;
            int i = y * W + x;
            int vi = lab[i];           if (!vi) return;
            int vn = lab[i - W + 1];   if (!vn) return;
            if (lab[i - W]) return;
            gunite(lab, vi - 1, vn - 1);
        }
    } else {                             // horizontal seam rows (ly == 0)
        int x = r & (W - 1);
        int y = (r >> 11) << 6;
        if (y == 0) return;
        int i = y * W + x;
        int vi = lab[i];               if (!vi) return;
        if (seg == 3) {
            if (x == 0) return;
            int vn = lab[i - W - 1];   if (!vn) return;
            if (lab[i - 1]) return;
            gunite(lab, vi - 1, vn - 1);
        } else if (seg == 4) {
            int vn = lab[i - W];       if (!vn) return;
            if (x > 0 && lab[i - 1]) return;
            gunite(lab, vi - 1, vn - 1);
        } else {
            if (x == W - 1) return;
            int vn = lab[i - W + 1];   if (!vn) return;
            gunite(lab, vi - 1, vn - 1);
        }
    }
}

__global__ __launch_bounds__(256)
void k_compress(int* __restrict__ lab) {
    int i = blockIdx.x * blockDim.x + threadIdx.x;
    if (i >= NPIX) return;
    int v = lab[i];
    if (v == 0 || v == i + 1) return;
    int r = gfind(lab, v - 1);
    lab[i] = r + 1;
}

extern "C" void kernel_launch(void* const* d_in, const int* in_sizes, int n_in,
                              void* d_out, int out_size, void* d_ws, size_t ws_size,
                              hipStream_t stream) {
    const float* prob = (const float*)d_in[0];
    int* lab = (int*)d_out;

    dim3 lgrid(W / TS, H / TS);
    dim3 lblock(TS, 16);
    k_local<<<lgrid, lblock, 0, stream>>>(prob, lab);

    const int nborder = 6 * 65536;
    k_border<<<nborder / 256, 256, 0, stream>>>(lab);

    k_compress<<<NPIX / 256, 256, 0, stream>>>(lab);
}